// Round 8
// baseline (108.881 us; speedup 1.0000x reference)
//
#include <hip/hip_runtime.h>

namespace {

constexpr float QSC = 0.18033688f;   // 0.125 * log2(e): fold 1/sqrt(d) and exp->exp2 into Q

typedef short bf16x8 __attribute__((ext_vector_type(8)));
typedef float f32x4 __attribute__((ext_vector_type(4)));

// hardware 2^x (v_exp_f32)
__device__ inline float exp2x(float x) { return __builtin_amdgcn_exp2f(x); }

// f32 -> bf16 round-to-nearest (half-up), packed pair (lo = a, hi = b) — cold paths
__device__ inline unsigned int pack2(float a, float b) {
  unsigned int ua = __builtin_bit_cast(unsigned int, a);
  unsigned int ub = __builtin_bit_cast(unsigned int, b);
  ua = (ua + 0x8000u) >> 16;
  ub = (ub + 0x8000u) & 0xFFFF0000u;
  return ua | ub;
}

// single-instruction packed f32->bf16 (hot loop): lo = bf16(a), hi = bf16(b)
__device__ inline unsigned int cvtpk(float a, float b) {
  unsigned int r;
  asm("v_cvt_pk_bf16_f32 %0, %1, %2" : "=v"(r) : "v"(a), "v"(b));
  return r;
}

__device__ inline bf16x8 ld16(const unsigned short* p) {
  uint4 u = *(const uint4*)p;
  return __builtin_bit_cast(bf16x8, u);
}

// v_permlane{32,16}_swap_b32: both operands are read-write.
__device__ inline void pswap32(unsigned int& a, unsigned int& b) {
  asm volatile("v_permlane32_swap_b32 %0, %1" : "+v"(a), "+v"(b));
}
__device__ inline void pswap16(unsigned int& a, unsigned int& b) {
  asm volatile("v_permlane16_swap_b32 %0, %1" : "+v"(a), "+v"(b));
}

// ---------------- pre-pass (V ONLY): V -> bf16 transposed [b][d][key] ----------------
// K is no longer pre-converted: fa reg-stages K straight from f32 and converts
// with cvt_pk in its ds_write phase (round-7 async-stage machinery). prep
// traffic 48 MB -> 24 MB. XCD affinity: b = bid & 7.
__global__ __launch_bounds__(256) void prep(const float* __restrict__ V,
                                            unsigned short* __restrict__ Vtb) {
  __shared__ float Vl[64 * 65];
  const int bid = blockIdx.x;          // 512 = 8 batches (XCD) * 64 key tiles
  const int b = bid & 7, kt = bid >> 3;
  const int tid = threadIdx.x;
  const float4* Vs4 = (const float4*)(V + ((size_t)b * 4096 + kt * 64) * 64);
  #pragma unroll
  for (int i = 0; i < 4; ++i) {
    int idx = tid + 256 * i;
    int row = idx >> 4, c4 = idx & 15;
    float4 tv = Vs4[idx];
    float* d = &Vl[row * 65 + c4 * 4];
    d[0] = tv.x; d[1] = tv.y; d[2] = tv.z; d[3] = tv.w;
  }
  __syncthreads();
  #pragma unroll
  for (int i = 0; i < 4; ++i) {
    int idx = tid + 256 * i;
    int dd = idx >> 4, kc = idx & 15;
    float a  = Vl[(kc * 4 + 0) * 65 + dd];
    float b2 = Vl[(kc * 4 + 1) * 65 + dd];
    float c  = Vl[(kc * 4 + 2) * 65 + dd];
    float e  = Vl[(kc * 4 + 3) * 65 + dd];
    *(uint2*)&Vtb[((size_t)b * 64 + dd) * 4096 + kt * 64 + kc * 4] =
        make_uint2(pack2(a, b2), pack2(c, e));
  }
}

// ---------------- main: 256 threads = 4 waves = 2 key-halves x 2 q-halves ----------------
// NS = cross-BLOCK key-splits; split s handles kt ≡ s (mod NS); merge kernel
// (separate launch) normalizes. XCD batch affinity: b = bid&7.
// Async-stage split (T14): K staged global->REG as f32 (converted to bf16 via
// cvt_pk at write time), V as bf16 from Vtb; ds_write to the next LDS buffer
// AFTER the body; per-iteration barrier = raw s_barrier + lgkmcnt(0) only (no
// vmcnt drain in the loop; compiler-counted vmcnt sits before the writes).
// Wave w -> (kh = w&1, qh = w>>1); half-K/half-V fragment reads; kh-pairs
// reduce O/l through LDS in the epilogue. LDS XOR-swizzled at 16B granularity;
// NO-MAX softmax; in-register P via permlane (T12); cvt_pk bf16 pack.
// smem ushort map: K0 at 0 | K1 at 4096 | V0 at 8192 | V1 at 12288
template <int NS>
__launch_bounds__(256, 4)
__global__ void fa_mfma(const float* __restrict__ Q,
                        float* __restrict__ O,
                        const float* __restrict__ K,         // f32 [b][key][d]
                        const unsigned short* __restrict__ Vtb,
                        float* __restrict__ Opart,   // (NS-1) partial slots in ws
                        float* __restrict__ lsum) {  // [NS][8*4096] row sums
  __shared__ __align__(16) unsigned short smem[16384];   // 32768 B

  const int bid = blockIdx.x;          // NS*512 blocks; XCD = batch = bid&7
  const int b  = bid & 7;
  const int rr = bid >> 3;             // 0..64*NS-1
  const int qt = 63 - rr / NS;
  const int s  = rr % NS;

  const int tid  = threadIdx.x;
  const int w    = tid >> 6;
  const int kh   = w & 1;        // key half
  const int qh   = w >> 1;       // q half
  const int lane = tid & 63;
  const int quad = lane >> 4;
  const int lc   = lane & 15;

  unsigned short* Kb0 = smem;
  unsigned short* Kb1 = smem + 4096;
  unsigned short* Vb0 = smem + 8192;
  unsigned short* Vb1 = smem + 12288;

  const float* Kf_g = K + (size_t)b * 4096 * 64;              // f32 [key][d]
  const unsigned short* Vt_g = Vtb + (size_t)b * 64 * 4096;   // bf16 [d][key]

  // staging geometry: wave w stages rows w*16..+15; lane -> row r0, phys chunk c0
  const int r0 = w * 16 + (lane >> 3);
  const int c0 = (lane & 7) ^ (r0 & 7);
  const size_t koff = (size_t)r0 * 64 + (size_t)c0 * 8;     // f32 idx, + kt*4096
  const size_t voff = (size_t)r0 * 4096 + (size_t)c0 * 8;   // ushort idx, + kt*64
  const int lw0 = w * 1024 + lane * 8;                      // LDS ushort idx, lane's 16B
  const int lw1 = lw0 + 512;

  // fragment-read swizzled chunk offsets (ushorts): K chunk (4ks+quad)^(lc&7)
  const int ph0 = (quad ^ (lc & 7)) * 8;
  const int ph1 = ((4 + quad) ^ (lc & 7)) * 8;
  // V chunk (kh*4+quad)^(lc&7)
  const int phv = ((kh * 4 + quad) ^ (lc & 7)) * 8;

  const size_t tile_off = ((size_t)b * 4096 + (size_t)qt * 64) * 64;
  const float* Qb = Q + tile_off;

  // iterations this split owns: kt = NS*i + s, kt <= qt (0 possible when qt < s)
  const int nIter = (qt >= s) ? ((qt - s) / NS + 1) : 0;

  // ---- prologue: issue tile-0 staging loads into registers ----
  float4 sK0 = {}, sK1 = {}, sK2 = {}, sK3 = {};   // K rows r0, r0+8 as f32
  uint4  sV0 = {}, sV1 = {};
  if (nIter > 0) {
    const float* gkp = Kf_g + (size_t)s * 4096 + koff;
    sK0 = *(const float4*)gkp;
    sK1 = *(const float4*)(gkp + 4);
    sK2 = *(const float4*)(gkp + 8 * 64);
    sK3 = *(const float4*)(gkp + 8 * 64 + 4);
    const unsigned short* gvp = Vt_g + (size_t)s * 64 + voff;
    sV0 = *(const uint4*)gvp;
    sV1 = *(const uint4*)(gvp + 8 * 4096);
  }

  // ---- Q fragments (B-operand), scaled by 0.125*log2e (hides staging latency) ----
  bf16x8 qf[2][2];   // [tq][ks]; rows qh*32 + tq*16 + lc, dims ks*32 + quad*8
  #pragma unroll
  for (int tq = 0; tq < 2; ++tq) {
    const float* qrow = Qb + (qh * 32 + tq * 16 + lc) * 64 + quad * 8;
    #pragma unroll
    for (int ks = 0; ks < 2; ++ks) {
      float4 x = *(const float4*)(qrow + ks * 32);
      float4 y = *(const float4*)(qrow + ks * 32 + 4);
      uint4 u = make_uint4(pack2(x.x * QSC, x.y * QSC), pack2(x.z * QSC, x.w * QSC),
                           pack2(y.x * QSC, y.y * QSC), pack2(y.z * QSC, y.w * QSC));
      qf[tq][ks] = __builtin_bit_cast(bf16x8, u);
    }
  }

  // ---- prologue: write tile 0 to buffer 0 (K converted via cvt_pk); issue tile-1 loads ----
  if (nIter > 0) {
    *(uint4*)&Kb0[lw0] = make_uint4(cvtpk(sK0.x, sK0.y), cvtpk(sK0.z, sK0.w),
                                    cvtpk(sK1.x, sK1.y), cvtpk(sK1.z, sK1.w));
    *(uint4*)&Kb0[lw1] = make_uint4(cvtpk(sK2.x, sK2.y), cvtpk(sK2.z, sK2.w),
                                    cvtpk(sK3.x, sK3.y), cvtpk(sK3.z, sK3.w));
    *(uint4*)&Vb0[lw0] = sV0;
    *(uint4*)&Vb0[lw1] = sV1;
    if (nIter > 1) {
      const int kt1 = NS + s;
      const float* gkp = Kf_g + (size_t)kt1 * 4096 + koff;
      sK0 = *(const float4*)gkp;
      sK1 = *(const float4*)(gkp + 4);
      sK2 = *(const float4*)(gkp + 8 * 64);
      sK3 = *(const float4*)(gkp + 8 * 64 + 4);
      const unsigned short* gvp = Vt_g + (size_t)kt1 * 64 + voff;
      sV0 = *(const uint4*)gvp;
      sV1 = *(const uint4*)(gvp + 8 * 4096);
    }
  }

  float l4[2] = {0.0f, 0.0f};   // per-lane partial row-sums, one per q-subtile
  f32x4 o[2][4];                // o[tq][td]
  #pragma unroll
  for (int tq = 0; tq < 2; ++tq)
    #pragma unroll
    for (int td = 0; td < 4; ++td) o[tq][td] = f32x4{0.f, 0.f, 0.f, 0.f};

  // ---- shared iteration body ----
  auto body = [&](const unsigned short* Kcur, const unsigned short* Vcur, bool diag) __attribute__((always_inline)) {
    // S^T: K rows kh*32 + tk*16 + lc (A), Q cols (B); K-dim = 64
    bf16x8 kf[2][2];
    #pragma unroll
    for (int tk = 0; tk < 2; ++tk) {
      kf[tk][0] = ld16(&Kcur[(kh * 32 + tk * 16 + lc) * 64 + ph0]);
      kf[tk][1] = ld16(&Kcur[(kh * 32 + tk * 16 + lc) * 64 + ph1]);
    }
    f32x4 st[2][2];   // [tk][tq]
    __builtin_amdgcn_s_setprio(1);
    #pragma unroll
    for (int tk = 0; tk < 2; ++tk)
      #pragma unroll
      for (int tq = 0; tq < 2; ++tq) {
        f32x4 c = {0.f, 0.f, 0.f, 0.f};
        c = __builtin_amdgcn_mfma_f32_16x16x32_bf16(kf[tk][0], qf[tq][0], c, 0, 0, 0);
        c = __builtin_amdgcn_mfma_f32_16x16x32_bf16(kf[tk][1], qf[tq][1], c, 0, 0, 0);
        st[tk][tq] = c;
      }
    __builtin_amdgcn_s_setprio(0);

    // no-max softmax: P = exp2(s); accumulate l; pack bf16 via cvt_pk
    unsigned int pc[2][2][2];   // [tk][tq][half]
    #pragma unroll
    for (int tk = 0; tk < 2; ++tk)
      #pragma unroll
      for (int tq = 0; tq < 2; ++tq) {
        float e[4];
        #pragma unroll
        for (int r = 0; r < 4; ++r) {
          float v = st[tk][tq][r];
          if (diag) {
            int key_l = kh * 32 + tk * 16 + quad * 4 + r;
            int q_l   = qh * 32 + tq * 16 + lc;
            if (key_l > q_l) v = -1e30f;   // exp2 -> 0
          }
          e[r] = exp2x(v);
        }
        l4[tq] += (e[0] + e[1]) + (e[2] + e[3]);
        pc[tk][tq][0] = cvtpk(e[0], e[1]);
        pc[tk][tq][1] = cvtpk(e[2], e[3]);
      }

    // PV: A = P rows (permlane-built, K-dim = wave's 32 keys), B = V^T slice
    bf16x8 vf[4];
    #pragma unroll
    for (int td = 0; td < 4; ++td)
      vf[td] = ld16(&Vcur[(td * 16 + lc) * 64 + phv]);
    __builtin_amdgcn_s_setprio(1);
    #pragma unroll
    for (int tq = 0; tq < 2; ++tq) {
      unsigned int x0 = pc[0][tq][0], y0 = pc[1][tq][0];
      unsigned int x1 = pc[0][tq][1], y1 = pc[1][tq][1];
      pswap32(x0, y0); pswap16(x0, y0);
      pswap32(x1, y1); pswap16(x1, y1);
      bf16x8 a = __builtin_bit_cast(bf16x8, make_uint4(x0, x1, y0, y1));
      #pragma unroll
      for (int td = 0; td < 4; ++td)
        o[tq][td] = __builtin_amdgcn_mfma_f32_16x16x32_bf16(a, vf[td], o[tq][td], 0, 0, 0);
    }
    __builtin_amdgcn_s_setprio(0);
  };

  // ---- main loop: body(i) | cvt+ds_write tile i+1 | issue loads tile i+2 ----
  for (int i = 0; i + 1 < nIter; ++i) {
    const unsigned short* Kcur = (i & 1) ? Kb1 : Kb0;
    const unsigned short* Vcur = (i & 1) ? Vb1 : Vb0;
    unsigned short* Knxt = (i & 1) ? Kb0 : Kb1;
    unsigned short* Vnxt = (i & 1) ? Vb0 : Vb1;

    // raw barrier: LDS writes of tile i visible; buffer (i+1) free for rewrite.
    // lgkmcnt(0) only — staging loads (vmcnt) stay in flight across the barrier.
    asm volatile("s_waitcnt lgkmcnt(0)" ::: "memory");
    __builtin_amdgcn_s_barrier();

    body(Kcur, Vcur, false);

    // write tile i+1 (regs loaded a full iteration ago; compiler-counted vmcnt)
    *(uint4*)&Knxt[lw0] = make_uint4(cvtpk(sK0.x, sK0.y), cvtpk(sK0.z, sK0.w),
                                     cvtpk(sK1.x, sK1.y), cvtpk(sK1.z, sK1.w));
    *(uint4*)&Knxt[lw1] = make_uint4(cvtpk(sK2.x, sK2.y), cvtpk(sK2.z, sK2.w),
                                     cvtpk(sK3.x, sK3.y), cvtpk(sK3.z, sK3.w));
    *(uint4*)&Vnxt[lw0] = sV0;
    *(uint4*)&Vnxt[lw1] = sV1;

    if (i + 2 < nIter) {   // issue tile i+2 staging loads (uniform branch)
      const int ktn = NS * (i + 2) + s;
      const float* gkp = Kf_g + (size_t)ktn * 4096 + koff;
      sK0 = *(const float4*)gkp;
      sK1 = *(const float4*)(gkp + 4);
      sK2 = *(const float4*)(gkp + 8 * 64);
      sK3 = *(const float4*)(gkp + 8 * 64 + 4);
      const unsigned short* gvp = Vt_g + (size_t)ktn * 64 + voff;
      sV0 = *(const uint4*)gvp;
      sV1 = *(const uint4*)(gvp + 8 * 4096);
    }
  }

  // ---- final iteration: masked iff this split owns the diagonal tile ----
  if (nIter > 0) {
    const int il = nIter - 1;
    const unsigned short* Kcur = (il & 1) ? Kb1 : Kb0;
    const unsigned short* Vcur = (il & 1) ? Vb1 : Vb0;
    asm volatile("s_waitcnt lgkmcnt(0)" ::: "memory");
    __builtin_amdgcn_s_barrier();
    body(Kcur, Vcur, (NS * il + s) == qt);
  }

  // ---- full drain, then reuse smem for the kh-pair O/l reduction ----
  __syncthreads();

  // cross-lane l reduce: sum the 4 quad replicas -> all lanes hold l[row=lc]
  #pragma unroll
  for (int tq = 0; tq < 2; ++tq) {
    l4[tq] += __shfl_xor(l4[tq], 16);
    l4[tq] += __shfl_xor(l4[tq], 32);
  }

  constexpr int MS = 66;
  float* buf  = (float*)smem;          // [64][MS] O partial from kh=1
  float* lbuf = buf + 64 * MS;         // [64] l partial from kh=1
  if (kh == 1) {
    #pragma unroll
    for (int tq = 0; tq < 2; ++tq) {
      #pragma unroll
      for (int r = 0; r < 4; ++r) {
        int row = qh * 32 + tq * 16 + quad * 4 + r;
        #pragma unroll
        for (int td = 0; td < 4; ++td)
          buf[row * MS + td * 16 + lc] = o[tq][td][r];
      }
      if (quad == 0) lbuf[qh * 32 + tq * 16 + lc] = l4[tq];
    }
  }
  __syncthreads();
  if (kh == 0) {
    #pragma unroll
    for (int tq = 0; tq < 2; ++tq) {
      l4[tq] += lbuf[qh * 32 + tq * 16 + lc];
      #pragma unroll
      for (int r = 0; r < 4; ++r) {
        int row = qh * 32 + tq * 16 + quad * 4 + r;
        #pragma unroll
        for (int td = 0; td < 4; ++td)
          o[tq][td][r] += buf[row * MS + td * 16 + lc];
      }
    }

    if constexpr (NS == 1) {
      float lv[2][4];
      #pragma unroll
      for (int tq = 0; tq < 2; ++tq) {
        float linv = 1.0f / l4[tq];
        #pragma unroll
        for (int r = 0; r < 4; ++r) lv[tq][r] = __shfl(linv, quad * 4 + r);
      }
      float* Ob = O + tile_off;
      #pragma unroll
      for (int tq = 0; tq < 2; ++tq)
        #pragma unroll
        for (int r = 0; r < 4; ++r) {
          int row = qh * 32 + tq * 16 + quad * 4 + r;
          #pragma unroll
          for (int td = 0; td < 4; ++td)
            Ob[row * 64 + td * 16 + lc] = o[tq][td][r] * lv[tq][r];
        }
    } else {
      // plain stores; the merge kernel (separate launch) is the synchronizer
      float* Oslot = (s == 0) ? (O + tile_off)
                              : (Opart + (size_t)(s - 1) * 2097152 + tile_off);
      #pragma unroll
      for (int tq = 0; tq < 2; ++tq) {
        #pragma unroll
        for (int r = 0; r < 4; ++r) {
          int row = qh * 32 + tq * 16 + quad * 4 + r;
          #pragma unroll
          for (int td = 0; td < 4; ++td)
            Oslot[row * 64 + td * 16 + lc] = o[tq][td][r];
        }
        if (quad == 0)
          lsum[s * 32768 + b * 4096 + qt * 64 + qh * 32 + tq * 16 + lc] = l4[tq];
      }
    }
  }
}

// ---------------- merge: O = (sum of NS partials) / (sum of NS row-sums) ----------------
// XCD affinity: block bid handles batch bid&7 -> reads fa's L2-resident partials.
template <int NS>
__global__ __launch_bounds__(256) void fa_merge(float* __restrict__ O,
                                               const float* __restrict__ Opart,
                                               const float* __restrict__ lsum) {
  const int b = blockIdx.x & 7;
  const int c = blockIdx.x >> 3;                       // 0..255 chunk within batch
  const int f = b * 262144 + c * 1024 + threadIdx.x * 4;   // f32 index
  const int row = f >> 6;
  float l = lsum[row];
  float4 acc = *(const float4*)&O[f];                  // split-0 partial lives in O
  #pragma unroll
  for (int s2 = 1; s2 < NS; ++s2) {
    l += lsum[s2 * 32768 + row];
    float4 p = *(const float4*)&Opart[(size_t)(s2 - 1) * 2097152 + f];
    acc.x += p.x; acc.y += p.y; acc.z += p.z; acc.w += p.w;
  }
  const float linv = 1.0f / l;
  acc.x *= linv; acc.y *= linv; acc.z *= linv; acc.w *= linv;
  *(float4*)&O[f] = acc;
}

}  // namespace

extern "C" void kernel_launch(void* const* d_in, const int* in_sizes, int n_in,
                              void* d_out, int out_size, void* d_ws, size_t ws_size,
                              hipStream_t stream) {
  const float* q = (const float*)d_in[0];
  const float* k = (const float*)d_in[1];
  const float* v = (const float*)d_in[2];
  float* out = (float*)d_out;

  unsigned short* Vtb = (unsigned short*)d_ws;                    // 4 MB
  float* Opart = (float*)(Vtb + (size_t)8 * 64 * 4096);           // (NS-1) x 8 MB
  auto need = [&](int ns) {
    return (size_t)8 * 64 * 4096 * 2 +                            // Vtb = 4 MB
           (size_t)(ns - 1) * 2097152 * 4 +                       // partials
           (size_t)ns * 32768 * 4;                                // lsum
  };

  prep<<<dim3(512), dim3(256), 0, stream>>>(v, Vtb);

  if (ws_size >= need(4)) {
    float* lsum = Opart + (size_t)3 * 2097152;
    fa_mfma<4><<<dim3(2048), dim3(256), 0, stream>>>(q, out, k, Vtb, Opart, lsum);
    fa_merge<4><<<dim3(2048), dim3(256), 0, stream>>>(out, Opart, lsum);
  } else if (ws_size >= need(2)) {
    float* lsum = Opart + (size_t)1 * 2097152;
    fa_mfma<2><<<dim3(1024), dim3(256), 0, stream>>>(q, out, k, Vtb, Opart, lsum);
    fa_merge<2><<<dim3(2048), dim3(256), 0, stream>>>(out, Opart, lsum);
  } else {
    fa_mfma<1><<<dim3(512), dim3(256), 0, stream>>>(q, out, k, Vtb, nullptr, nullptr);
  }
}

// Round 9
// 108.378 us; speedup vs baseline: 1.0046x; 1.0046x over previous
//
#include <hip/hip_runtime.h>

namespace {

constexpr float QSC = 0.18033688f;   // 0.125 * log2(e): fold 1/sqrt(d) and exp->exp2 into Q

typedef short bf16x8 __attribute__((ext_vector_type(8)));
typedef float f32x4 __attribute__((ext_vector_type(4)));

typedef __attribute__((address_space(3))) unsigned int lds_u32;
typedef __attribute__((address_space(1))) const unsigned int gbl_u32;

// hardware 2^x (v_exp_f32)
__device__ inline float exp2x(float x) { return __builtin_amdgcn_exp2f(x); }

// f32 -> bf16 round-to-nearest (half-up), packed pair (lo = a, hi = b) — cold paths
__device__ inline unsigned int pack2(float a, float b) {
  unsigned int ua = __builtin_bit_cast(unsigned int, a);
  unsigned int ub = __builtin_bit_cast(unsigned int, b);
  ua = (ua + 0x8000u) >> 16;
  ub = (ub + 0x8000u) & 0xFFFF0000u;
  return ua | ub;
}

// single-instruction packed f32->bf16 (hot loop): lo = bf16(a), hi = bf16(b)
__device__ inline unsigned int cvtpk(float a, float b) {
  unsigned int r;
  asm("v_cvt_pk_bf16_f32 %0, %1, %2" : "=v"(r) : "v"(a), "v"(b));
  return r;
}

// async global->LDS, 16B per lane; LDS dest = wave-uniform base + lane*16
__device__ inline void gl_lds16(const unsigned short* g, unsigned short* l) {
  __builtin_amdgcn_global_load_lds((gbl_u32*)g, (lds_u32*)l, 16, 0, 0);
}

__device__ inline bf16x8 ld16(const unsigned short* p) {
  uint4 u = *(const uint4*)p;
  return __builtin_bit_cast(bf16x8, u);
}

// v_permlane{32,16}_swap_b32: both operands are read-write.
__device__ inline void pswap32(unsigned int& a, unsigned int& b) {
  asm volatile("v_permlane32_swap_b32 %0, %1" : "+v"(a), "+v"(b));
}
__device__ inline void pswap16(unsigned int& a, unsigned int& b) {
  asm volatile("v_permlane16_swap_b32 %0, %1" : "+v"(a), "+v"(b));
}

// ---------------- pre-pass: K -> bf16 [b][key][d]; V -> bf16 transposed [b][d][key] ----------------
// XCD affinity: b = bid & 7 -> batch-b tiles produced on XCD b (warm L2 for fa).
__global__ __launch_bounds__(256) void prep(const float* __restrict__ K,
                                            const float* __restrict__ V,
                                            unsigned short* __restrict__ Kbf,
                                            unsigned short* __restrict__ Vtb) {
  __shared__ float Vl[64 * 65];
  const int bid = blockIdx.x;          // 512 = 8 batches (XCD) * 64 key tiles
  const int b = bid & 7, kt = bid >> 3;
  const int tid = threadIdx.x;
  const float4* Ks4 = (const float4*)(K + ((size_t)b * 4096 + kt * 64) * 64);
  const float4* Vs4 = (const float4*)(V + ((size_t)b * 4096 + kt * 64) * 64);
  #pragma unroll
  for (int i = 0; i < 4; ++i) {
    int idx = tid + 256 * i;
    int row = idx >> 4, c4 = idx & 15;
    float4 t = Ks4[idx];
    *(uint2*)&Kbf[((size_t)b * 4096 + kt * 64 + row) * 64 + c4 * 4] =
        make_uint2(pack2(t.x, t.y), pack2(t.z, t.w));
    float4 tv = Vs4[idx];
    float* d = &Vl[row * 65 + c4 * 4];
    d[0] = tv.x; d[1] = tv.y; d[2] = tv.z; d[3] = tv.w;
  }
  __syncthreads();
  #pragma unroll
  for (int i = 0; i < 4; ++i) {
    int idx = tid + 256 * i;
    int dd = idx >> 4, kc = idx & 15;
    float a  = Vl[(kc * 4 + 0) * 65 + dd];
    float b2 = Vl[(kc * 4 + 1) * 65 + dd];
    float c  = Vl[(kc * 4 + 2) * 65 + dd];
    float e  = Vl[(kc * 4 + 3) * 65 + dd];
    *(uint2*)&Vtb[((size_t)b * 64 + dd) * 4096 + kt * 64 + kc * 4] =
        make_uint2(pack2(a, b2), pack2(c, e));
  }
}

// ---------------- main: 512 threads = 8 waves = 2 key-halves x 4 q-quarters ----------------
// OCCUPANCY-DOUBLING REVISION: the r2/r4 scaling data shows a ~1100-cyc serial
// chain per iteration vs ~150-cyc issue per wave -> need ~8 wave-streams/SIMD.
// 512-thr blocks with VGPR<=64 (__launch_bounds__(512,8)) give 4 blocks/CU x
// 8 waves = 32 waves/CU = 8/SIMD (2x the previous config). Per wave: 16 q-rows
// x 32 keys (o=16, qf=8, st=8 VGPR). Staging = global_load_lds (0 staging
// VGPRs, 2 ops/wave/iter); its vmcnt(0)+barrier drain is hidden by the other
// 3 blocks' 24 waves. NS=2 cross-block key-split (kt ≡ s mod 2), merge kernel
// normalizes; kh-pairs reduce O/l through LDS in the epilogue.
// LDS XOR-swizzled at 16B granularity; NO-MAX softmax; in-register P via
// permlane (T12); cvt_pk bf16 pack. XCD batch affinity b = bid&7.
// smem ushort map: K0 at 0 | K1 at 4096 | V0 at 8192 | V1 at 12288 (32 KB)
template <int NS>
__launch_bounds__(512, 8)
__global__ void fa_mfma(const float* __restrict__ Q,
                        float* __restrict__ O,
                        const unsigned short* __restrict__ Kbf,
                        const unsigned short* __restrict__ Vtb,
                        float* __restrict__ Opart,   // (NS-1) partial slots in ws
                        float* __restrict__ lsum) {  // [NS][8*4096] row sums
  __shared__ __align__(16) unsigned short smem[16384];   // 32768 B

  const int bid = blockIdx.x;          // XCD = batch = bid&7; longest qt first
  int b, qt, s;
  if constexpr (NS == 2) { qt = 63 - (bid >> 4); b = bid & 7; s = (bid >> 3) & 1; }
  else                   { qt = 63 - (bid >> 3); b = bid & 7; s = 0; }

  const int tid  = threadIdx.x;
  const int w    = tid >> 6;     // 0..7
  const int kh   = w & 1;        // key half
  const int qh   = w >> 1;       // q quarter (0..3)
  const int lane = tid & 63;
  const int quad = lane >> 4;
  const int lc   = lane & 15;

  unsigned short* Kb0 = smem;
  unsigned short* Kb1 = smem + 4096;
  unsigned short* Vb0 = smem + 8192;
  unsigned short* Vb1 = smem + 12288;

  const unsigned short* Kt_g = Kbf + (size_t)b * 4096 * 64;   // [key][d]
  const unsigned short* Vt_g = Vtb + (size_t)b * 64 * 4096;   // [d][key]

  // staging geometry: wave w stages K rows / V d-rows w*8..+7 (one gl_lds16 each)
  const int r0 = w * 8 + (lane >> 3);
  const int c0 = (lane & 7) ^ (r0 & 7);

  // fragment-read swizzled chunk offsets (ushorts): K chunk (4ks+quad)^(lc&7)
  const int ph0 = (quad ^ (lc & 7)) * 8;
  const int ph1 = ((4 + quad) ^ (lc & 7)) * 8;
  // V chunk (kh*4+quad)^(lc&7)
  const int phv = ((kh * 4 + quad) ^ (lc & 7)) * 8;

  const size_t tile_off = ((size_t)b * 4096 + (size_t)qt * 64) * 64;
  const float* Qb = Q + tile_off;

  // iterations this split owns: kt = NS*i + s, kt <= qt (0 possible when qt < s)
  const int nIter = (qt >= s) ? ((qt - s) / NS + 1) : 0;

  // ---- prologue: stage K(kt0), V(kt0) into buffer 0 (clamped if nIter==0) ----
  {
    const int kt0 = (s <= qt) ? s : qt;
    gl_lds16(Kt_g + (size_t)(kt0 * 64 + r0) * 64 + c0 * 8, Kb0 + w * 512);
    gl_lds16(Vt_g + (size_t)r0 * 4096 + kt0 * 64 + c0 * 8, Vb0 + w * 512);
  }

  // ---- Q fragments (B-operand), rows qh*16+lc, scaled by 0.125*log2e ----
  bf16x8 qf[2];
  {
    const float* qrow = Qb + (qh * 16 + lc) * 64 + quad * 8;
    #pragma unroll
    for (int ks = 0; ks < 2; ++ks) {
      float4 x = *(const float4*)(qrow + ks * 32);
      float4 y = *(const float4*)(qrow + ks * 32 + 4);
      uint4 u = make_uint4(pack2(x.x * QSC, x.y * QSC), pack2(x.z * QSC, x.w * QSC),
                           pack2(y.x * QSC, y.y * QSC), pack2(y.z * QSC, y.w * QSC));
      qf[ks] = __builtin_bit_cast(bf16x8, u);
    }
  }

  float l_i = 0.0f;
  f32x4 o[4];
  #pragma unroll
  for (int td = 0; td < 4; ++td) o[td] = f32x4{0.f, 0.f, 0.f, 0.f};

  const int q_l = qh * 16 + lc;

  // ---- shared iteration body ----
  auto body = [&](const unsigned short* Kcur, const unsigned short* Vcur, bool diag) __attribute__((always_inline)) {
    // S^T: K rows kh*32 + tk*16 + lc (A), Q cols (B); K-dim = 64
    bf16x8 kf[2][2];
    #pragma unroll
    for (int tk = 0; tk < 2; ++tk) {
      kf[tk][0] = ld16(&Kcur[(kh * 32 + tk * 16 + lc) * 64 + ph0]);
      kf[tk][1] = ld16(&Kcur[(kh * 32 + tk * 16 + lc) * 64 + ph1]);
    }
    f32x4 st[2];
    __builtin_amdgcn_s_setprio(1);
    #pragma unroll
    for (int tk = 0; tk < 2; ++tk) {
      f32x4 c = {0.f, 0.f, 0.f, 0.f};
      c = __builtin_amdgcn_mfma_f32_16x16x32_bf16(kf[tk][0], qf[0], c, 0, 0, 0);
      c = __builtin_amdgcn_mfma_f32_16x16x32_bf16(kf[tk][1], qf[1], c, 0, 0, 0);
      st[tk] = c;
    }
    __builtin_amdgcn_s_setprio(0);

    // no-max softmax: P = exp2(s); accumulate l; pack bf16 via cvt_pk
    unsigned int pc[2][2];
    #pragma unroll
    for (int tk = 0; tk < 2; ++tk) {
      float e[4];
      #pragma unroll
      for (int r = 0; r < 4; ++r) {
        float v = st[tk][r];
        if (diag) {
          int key_l = kh * 32 + tk * 16 + quad * 4 + r;
          if (key_l > q_l) v = -1e30f;   // exp2 -> 0
        }
        e[r] = exp2x(v);
      }
      l_i += (e[0] + e[1]) + (e[2] + e[3]);
      pc[tk][0] = cvtpk(e[0], e[1]);
      pc[tk][1] = cvtpk(e[2], e[3]);
    }

    // PV: A = P rows (permlane-built, K-dim = wave's 32 keys), B = V^T slice
    bf16x8 vf[4];
    #pragma unroll
    for (int td = 0; td < 4; ++td)
      vf[td] = ld16(&Vcur[(td * 16 + lc) * 64 + phv]);
    __builtin_amdgcn_s_setprio(1);
    {
      unsigned int x0 = pc[0][0], y0 = pc[1][0];
      unsigned int x1 = pc[0][1], y1 = pc[1][1];
      pswap32(x0, y0); pswap16(x0, y0);
      pswap32(x1, y1); pswap16(x1, y1);
      bf16x8 a = __builtin_bit_cast(bf16x8, make_uint4(x0, x1, y0, y1));
      #pragma unroll
      for (int td = 0; td < 4; ++td)
        o[td] = __builtin_amdgcn_mfma_f32_16x16x32_bf16(a, vf[td], o[td], 0, 0, 0);
    }
    __builtin_amdgcn_s_setprio(0);
  };

  // ---- main loop: unmasked iterations with distance-1 gl_lds prefetch ----
  for (int i = 0; i + 1 < nIter; ++i) {
    const unsigned short* Kcur = (i & 1) ? Kb1 : Kb0;
    const unsigned short* Vcur = (i & 1) ? Vb1 : Vb0;
    unsigned short* Knxt = (i & 1) ? Kb0 : Kb1;
    unsigned short* Vnxt = (i & 1) ? Vb0 : Vb1;

    // own prefetches from previous iteration have landed; barrier makes all
    // waves' staging visible AND retires reads of the buffer we overwrite next.
    // The drain stall is the bet: 24 other resident waves/CU now cover it.
    asm volatile("s_waitcnt vmcnt(0)" ::: "memory");
    __builtin_amdgcn_s_barrier();

    const int ktn = NS * (i + 1) + s;
    gl_lds16(Kt_g + (size_t)(ktn * 64 + r0) * 64 + c0 * 8, Knxt + w * 512);
    gl_lds16(Vt_g + (size_t)r0 * 4096 + ktn * 64 + c0 * 8, Vnxt + w * 512);

    body(Kcur, Vcur, false);
  }

  // ---- final iteration: masked iff this split owns the diagonal tile ----
  if (nIter > 0) {
    const int il = nIter - 1;
    const unsigned short* Kcur = (il & 1) ? Kb1 : Kb0;
    const unsigned short* Vcur = (il & 1) ? Vb1 : Vb0;
    asm volatile("s_waitcnt vmcnt(0)" ::: "memory");
    __builtin_amdgcn_s_barrier();
    body(Kcur, Vcur, (NS * il + s) == qt);
  }

  // ---- full drain (incl. unconsumed prologue stage when nIter==0),
  //      then reuse smem for the kh-pair O/l reduction ----
  __syncthreads();

  // cross-lane l reduce: sum the 4 quad replicas -> all lanes hold l[row=lc]
  l_i += __shfl_xor(l_i, 16);
  l_i += __shfl_xor(l_i, 32);

  constexpr int MS = 66;
  float* buf  = (float*)smem;          // [64][MS] O partial from kh=1
  float* lbuf = buf + 64 * MS;         // [64] l partial from kh=1
  if (kh == 1) {
    #pragma unroll
    for (int r = 0; r < 4; ++r) {
      int row = qh * 16 + quad * 4 + r;
      #pragma unroll
      for (int td = 0; td < 4; ++td)
        buf[row * MS + td * 16 + lc] = o[td][r];
    }
    if (quad == 0) lbuf[qh * 16 + lc] = l_i;
  }
  __syncthreads();
  if (kh == 0) {
    l_i += lbuf[qh * 16 + lc];
    #pragma unroll
    for (int r = 0; r < 4; ++r) {
      int row = qh * 16 + quad * 4 + r;
      #pragma unroll
      for (int td = 0; td < 4; ++td)
        o[td][r] += buf[row * MS + td * 16 + lc];
    }

    if constexpr (NS == 1) {
      float linv = 1.0f / l_i;
      float lv[4];
      #pragma unroll
      for (int r = 0; r < 4; ++r) lv[r] = __shfl(linv, quad * 4 + r);
      float* Ob = O + tile_off;
      #pragma unroll
      for (int r = 0; r < 4; ++r) {
        int row = qh * 16 + quad * 4 + r;
        #pragma unroll
        for (int td = 0; td < 4; ++td)
          Ob[row * 64 + td * 16 + lc] = o[td][r] * lv[r];
      }
    } else {
      // plain stores; the merge kernel (separate launch) is the synchronizer
      float* Oslot = (s == 0) ? (O + tile_off) : (Opart + tile_off);
      #pragma unroll
      for (int r = 0; r < 4; ++r) {
        int row = qh * 16 + quad * 4 + r;
        #pragma unroll
        for (int td = 0; td < 4; ++td)
          Oslot[row * 64 + td * 16 + lc] = o[td][r];
      }
      if (quad == 0)
        lsum[s * 32768 + b * 4096 + qt * 64 + qh * 16 + lc] = l_i;
    }
  }
}

// ---------------- merge: O = (sum of NS partials) / (sum of NS row-sums) ----------------
// XCD affinity: block bid handles batch bid&7 -> reads fa's L2-resident partials.
template <int NS>
__global__ __launch_bounds__(256) void fa_merge(float* __restrict__ O,
                                               const float* __restrict__ Opart,
                                               const float* __restrict__ lsum) {
  const int b = blockIdx.x & 7;
  const int c = blockIdx.x >> 3;                       // 0..255 chunk within batch
  const int f = b * 262144 + c * 1024 + threadIdx.x * 4;   // f32 index
  const int row = f >> 6;
  float l = lsum[row];
  float4 acc = *(const float4*)&O[f];                  // split-0 partial lives in O
  #pragma unroll
  for (int s2 = 1; s2 < NS; ++s2) {
    l += lsum[s2 * 32768 + row];
    float4 p = *(const float4*)&Opart[(size_t)(s2 - 1) * 2097152 + f];
    acc.x += p.x; acc.y += p.y; acc.z += p.z; acc.w += p.w;
  }
  const float linv = 1.0f / l;
  acc.x *= linv; acc.y *= linv; acc.z *= linv; acc.w *= linv;
  *(float4*)&O[f] = acc;
}

}  // namespace

extern "C" void kernel_launch(void* const* d_in, const int* in_sizes, int n_in,
                              void* d_out, int out_size, void* d_ws, size_t ws_size,
                              hipStream_t stream) {
  const float* q = (const float*)d_in[0];
  const float* k = (const float*)d_in[1];
  const float* v = (const float*)d_in[2];
  float* out = (float*)d_out;

  unsigned short* Kbf = (unsigned short*)d_ws;                    // 4 MB
  unsigned short* Vtb = Kbf + (size_t)8 * 4096 * 64;              // 4 MB
  float* Opart = (float*)(Vtb + (size_t)8 * 4096 * 64);           // (NS-1) x 8 MB
  auto need = [&](int ns) {
    return (size_t)16 * 1024 * 1024 / 2 +                         // Kbf+Vtb = 8 MB
           (size_t)(ns - 1) * 2097152 * 4 +                       // partials
           (size_t)ns * 32768 * 4;                                // lsum
  };

  prep<<<dim3(512), dim3(256), 0, stream>>>(k, v, Kbf, Vtb);

  if (ws_size >= need(2)) {
    float* lsum = Opart + (size_t)1 * 2097152;
    fa_mfma<2><<<dim3(1024), dim3(512), 0, stream>>>(q, out, Kbf, Vtb, Opart, lsum);
    fa_merge<2><<<dim3(2048), dim3(256), 0, stream>>>(out, Opart, lsum);
  } else {
    fa_mfma<1><<<dim3(512), dim3(512), 0, stream>>>(q, out, Kbf, Vtb, nullptr, nullptr);
  }
}